// Round 17
// baseline (79.018 us; speedup 1.0000x reference)
//
#include <hip/hip_runtime.h>
#include <hip/hip_fp16.h>

constexpr int N_IN    = 128;
constexpr int N_OUT   = 32;
constexpr int LOG_R   = 6;
constexpr int RANGE   = 1 << LOG_R;  // 64 nodes per bucket
constexpr int MAXNB   = 2048;        // max buckets
constexpr int NCC     = 256;         // edge chunks
constexpr int FBLK    = 512;         // fused kernel threads
constexpr int CHUNK_P = 2048;        // staged pairs per conv block (fast path)
constexpr int CAP     = 6272;        // max staged edges per chunk (epc<=6252)

// fused-kernel LDS layout (bytes)
constexpr int OFF_PAIRS = 0;                         // int2[CAP]   = 50176
constexpr int OFF_BKT   = OFF_PAIRS + CAP * 8;       // u16[CAP]    = 12544
constexpr int OFF_HIST  = OFF_BKT + CAP * 2;         // int[MAXNB]  = 8192
constexpr int OFF_WSCAN = OFF_HIST + MAXNB * 4;      // int[FBLK]   = 2048
constexpr int SMEM_SZ   = OFF_WSCAN + FBLK * 4;      // 72960 B (~71.3 KB)

union H4 { uint2 u; __half2 h2[2]; };
union H8 { uint4 u; __half2 h2[4]; };

// ---------------- fused: LDS-staged partition role + gemm role -------------
// Partition role (blocks 0..ncc-1): ONE global pass stages (pair,bucket) in
// LDS while histogramming; in-LDS scan; scatter pass reads LDS (no global
// re-read, short dependency chains). Gemm role (blocks >= ncc): h = feat@W.
__global__ __launch_bounds__(FBLK) void gemm_part_k(
    const float* __restrict__ feat, const float* __restrict__ W,
    const int* __restrict__ src, const int* __restrict__ dst,
    const float* __restrict__ ew, __half* __restrict__ h,
    int* __restrict__ tbl, int2* __restrict__ sw,
    int n, int E, int NB, int epc, int ncc)
{
    __shared__ __align__(16) char smem[SMEM_SZ];
    const int tid = threadIdx.x;

    if ((int)blockIdx.x < ncc) {
        // ================= partition role =================
        int2*           pl    = (int2*)(smem + OFF_PAIRS);
        unsigned short* bk    = (unsigned short*)(smem + OFF_BKT);
        int*            hist  = (int*)(smem + OFF_HIST);
        int*            wscan = (int*)(smem + OFF_WSCAN);

        const int c   = blockIdx.x;
        const int e0  = c * epc;
        const int e1  = min(e0 + epc, E);
        const int m   = max(e1 - e0, 0);
        const int m4  = m & ~3;
        const int slots = (NB + FBLK - 1) / FBLK;

        for (int i = tid; i < NB; i += FBLK) hist[i] = 0;
        __syncthreads();

        // pass 1: single global read -> stage pairs+buckets in LDS + hist
        for (int o = tid * 4; o < m4; o += FBLK * 4) {
            int4   sv = *reinterpret_cast<const int4*>(src + e0 + o);
            int4   dv = *reinterpret_cast<const int4*>(dst + e0 + o);
            float4 wv = *reinterpret_cast<const float4*>(ew + e0 + o);
            int b0 = dv.x >> LOG_R, b1 = dv.y >> LOG_R;
            int b2 = dv.z >> LOG_R, b3 = dv.w >> LOG_R;
            atomicAdd(&hist[b0], 1);
            atomicAdd(&hist[b1], 1);
            atomicAdd(&hist[b2], 1);
            atomicAdd(&hist[b3], 1);
            pl[o + 0] = make_int2(sv.x | ((dv.x & (RANGE - 1)) << 17), __float_as_int(wv.x));
            pl[o + 1] = make_int2(sv.y | ((dv.y & (RANGE - 1)) << 17), __float_as_int(wv.y));
            pl[o + 2] = make_int2(sv.z | ((dv.z & (RANGE - 1)) << 17), __float_as_int(wv.z));
            pl[o + 3] = make_int2(sv.w | ((dv.w & (RANGE - 1)) << 17), __float_as_int(wv.w));
            bk[o + 0] = (unsigned short)b0;
            bk[o + 1] = (unsigned short)b1;
            bk[o + 2] = (unsigned short)b2;
            bk[o + 3] = (unsigned short)b3;
        }
        if (m4 + tid < m) {
            int e = e0 + m4 + tid;
            int d = dst[e];
            int b = d >> LOG_R;
            atomicAdd(&hist[b], 1);
            pl[m4 + tid] = make_int2(src[e] | ((d & (RANGE - 1)) << 17), __float_as_int(ew[e]));
            bk[m4 + tid] = (unsigned short)b;
        }
        __syncthreads();

        // exclusive scan over NB counters
        int tsum = 0;
        int base = tid * slots;
        for (int j = 0; j < slots; ++j) {
            int idx = base + j;
            if (idx < NB) tsum += hist[idx];
        }
        wscan[tid] = tsum;
        __syncthreads();
        for (int off = 1; off < FBLK; off <<= 1) {
            int x = (tid >= off) ? wscan[tid - off] : 0;
            __syncthreads();
            wscan[tid] += x;
            __syncthreads();
        }
        int run = wscan[tid] - tsum;
        __syncthreads();
        for (int j = 0; j < slots; ++j) {
            int idx = base + j;
            if (idx < NB) {
                int cval = hist[idx];
                tbl[(size_t)c * (NB + 1) + idx] = run;
                hist[idx] = run;                        // becomes cursor
                run += cval;
            }
        }
        if (tid == 0) tbl[(size_t)c * (NB + 1) + NB] = m;
        __syncthreads();

        // pass 2: scatter from LDS (no global re-read)
        int2* outp = sw + (size_t)c * epc;
        for (int i = tid; i < m; i += FBLK) {
            int b = bk[i];
            int pos = atomicAdd(&hist[b], 1);
            outp[pos] = pl[i];
        }
    } else {
        // ================= gemm role =================
        float* Ws = (float*)smem;                   // 16 KB of the buffer
        for (int i = tid; i < (N_IN * N_OUT) / 4; i += FBLK)
            reinterpret_cast<float4*>(Ws)[i] = reinterpret_cast<const float4*>(W)[i];
        __syncthreads();

        int gid = ((int)blockIdx.x - ncc) * FBLK + tid;
        int row = gid >> 3;
        if (row >= n) return;
        int cg = (gid & 7) * 4;

        const float4* frow = reinterpret_cast<const float4*>(feat + (size_t)row * N_IN);
        float4 acc = make_float4(0.f, 0.f, 0.f, 0.f);
        #pragma unroll
        for (int k4 = 0; k4 < N_IN / 4; ++k4) {
            float4 f = frow[k4];
            int k = k4 * 4;
            float4 w0 = *reinterpret_cast<const float4*>(&Ws[(k + 0) * N_OUT + cg]);
            float4 w1 = *reinterpret_cast<const float4*>(&Ws[(k + 1) * N_OUT + cg]);
            float4 w2 = *reinterpret_cast<const float4*>(&Ws[(k + 2) * N_OUT + cg]);
            float4 w3 = *reinterpret_cast<const float4*>(&Ws[(k + 3) * N_OUT + cg]);
            acc.x += f.x * w0.x + f.y * w1.x + f.z * w2.x + f.w * w3.x;
            acc.y += f.x * w0.y + f.y * w1.y + f.z * w2.y + f.w * w3.y;
            acc.z += f.x * w0.z + f.y * w1.z + f.z * w2.z + f.w * w3.z;
            acc.w += f.x * w0.w + f.y * w1.w + f.z * w2.w + f.w * w3.w;
        }
        H4 v;
        v.h2[0] = __float22half2_rn(make_float2(acc.x, acc.y));
        v.h2[1] = __float22half2_rn(make_float2(acc.z, acc.w));
        *reinterpret_cast<uint2*>(h + (size_t)row * N_OUT + cg) = v.u;
    }
}

// ---------------- conv6: single-read stage + u16 order + 8-wide gather -----
__global__ __launch_bounds__(256) void conv6_k(
    const __half* __restrict__ h, const int2* __restrict__ sw,
    const int* __restrict__ tbl, float* __restrict__ out,
    int n, int NB, int ncc, int epc)
{
    __shared__ int2 pairs[CHUNK_P];            // 16 KB
    __shared__ unsigned short order[CHUNK_P];  // 4 KB
    __shared__ int cnt[RANGE];
    __shared__ int sc[RANGE];
    __shared__ int start[RANGE + 1];
    __shared__ int cur[RANGE];
    __shared__ int rs[NCC];
    __shared__ int ps[NCC + 1];
    __shared__ int stmp[256];

    const int b    = blockIdx.x;
    const int tid  = threadIdx.x;
    const int node = tid >> 2;          // 0..63 (group of 4)
    const int cg8  = (tid & 3) * 8;     // 8 f16 columns per thread

    int len = 0;
    if (tid < ncc) {
        int s0 = tbl[(size_t)tid * (NB + 1) + b];
        int s1 = tbl[(size_t)tid * (NB + 1) + b + 1];
        rs[tid] = s0;
        len = s1 - s0;
    }
    stmp[tid] = len;
    __syncthreads();
    for (int off = 1; off < 256; off <<= 1) {
        int x = (tid >= off) ? stmp[tid - off] : 0;
        __syncthreads();
        stmp[tid] += x;
        __syncthreads();
    }
    ps[tid + 1] = stmp[tid];
    if (tid == 0) ps[0] = 0;
    __syncthreads();
    const int deg = ps[ncc];

    float4 acc01 = make_float4(0.f, 0.f, 0.f, 0.f);
    float4 acc23 = make_float4(0.f, 0.f, 0.f, 0.f);

    #define GLOAD(p, f0, f1, f2, f3)                                           \
        H8 _x##f0;                                                             \
        _x##f0.u = *reinterpret_cast<const uint4*>(                            \
            h + (size_t)((p).x & 0x1FFFF) * N_OUT + cg8);                      \
        float2 f0 = __half22float2(_x##f0.h2[0]);                              \
        float2 f1 = __half22float2(_x##f0.h2[1]);                              \
        float2 f2 = __half22float2(_x##f0.h2[2]);                              \
        float2 f3 = __half22float2(_x##f0.h2[3]);
    #define GACC(p, f0, f1, f2, f3)                                            \
    {                                                                          \
        float wv = __int_as_float((p).y);                                      \
        acc01.x += f0.x * wv; acc01.y += f0.y * wv;                            \
        acc01.z += f1.x * wv; acc01.w += f1.y * wv;                            \
        acc23.x += f2.x * wv; acc23.y += f2.y * wv;                            \
        acc23.z += f3.x * wv; acc23.w += f3.y * wv;                            \
    }

    if (deg <= CHUNK_P) {
        if (tid < RANGE) cnt[tid] = 0;
        __syncthreads();

        {
            int d0 = ps[tid];
            int l  = ps[tid + 1] - d0;
            const int2* sp = sw + (size_t)tid * epc + rs[tid];
            for (int j = 0; j < l; ++j) {
                int2 p = sp[j];
                pairs[d0 + j] = p;
                atomicAdd(&cnt[p.x >> 17], 1);
            }
        }
        __syncthreads();

        int v = 0;
        if (tid < RANGE) { v = cnt[tid]; sc[tid] = v; }
        __syncthreads();
        #pragma unroll
        for (int off = 1; off < RANGE; off <<= 1) {
            int x = (tid < RANGE && tid >= off) ? sc[tid - off] : 0;
            __syncthreads();
            if (tid < RANGE) sc[tid] += x;
            __syncthreads();
        }
        if (tid < RANGE) { start[tid] = sc[tid] - v; cur[tid] = sc[tid] - v; }
        if (tid == RANGE - 1) start[RANGE] = sc[RANGE - 1];
        __syncthreads();

        for (int i = tid; i < deg; i += 256) {
            int loc = pairs[i].x >> 17;
            int pos = atomicAdd(&cur[loc], 1);
            order[pos] = (unsigned short)i;
        }
        __syncthreads();

        int k  = start[node];
        int ke = start[node + 1];
        // 8-wide batch for deep MLP
        for (; k + 7 < ke; k += 8) {
            int2 q0 = pairs[order[k + 0]], q1 = pairs[order[k + 1]];
            int2 q2 = pairs[order[k + 2]], q3 = pairs[order[k + 3]];
            int2 q4 = pairs[order[k + 4]], q5 = pairs[order[k + 5]];
            int2 q6 = pairs[order[k + 6]], q7 = pairs[order[k + 7]];
            GLOAD(q0, m0, m1, m2, m3)
            GLOAD(q1, n0, n1, n2, n3)
            GLOAD(q2, o0, o1, o2, o3)
            GLOAD(q3, p0, p1, p2, p3)
            GLOAD(q4, r0, r1, r2, r3)
            GLOAD(q5, s0, s1, s2, s3)
            GLOAD(q6, t0, t1, t2, t3)
            GLOAD(q7, u0, u1, u2, u3)
            GACC(q0, m0, m1, m2, m3)
            GACC(q1, n0, n1, n2, n3)
            GACC(q2, o0, o1, o2, o3)
            GACC(q3, p0, p1, p2, p3)
            GACC(q4, r0, r1, r2, r3)
            GACC(q5, s0, s1, s2, s3)
            GACC(q6, t0, t1, t2, t3)
            GACC(q7, u0, u1, u2, u3)
        }
        for (; k + 3 < ke; k += 4) {
            int2 q0 = pairs[order[k + 0]], q1 = pairs[order[k + 1]];
            int2 q2 = pairs[order[k + 2]], q3 = pairs[order[k + 3]];
            GLOAD(q0, a0, a1, a2, a3)
            GLOAD(q1, b0, b1, b2, b3)
            GLOAD(q2, c0, c1, c2, c3)
            GLOAD(q3, d0, d1, d2, d3)
            GACC(q0, a0, a1, a2, a3)
            GACC(q1, b0, b1, b2, b3)
            GACC(q2, c0, c1, c2, c3)
            GACC(q3, d0, d1, d2, d3)
        }
        for (; k < ke; ++k) {
            int2 q = pairs[order[k]];
            GLOAD(q, e0, e1, e2, e3)
            GACC(q, e0, e1, e2, e3)
        }
    } else {
        for (int cbase = 0; cbase < deg; cbase += CHUNK_P) {
            const int m = min(CHUNK_P, deg - cbase);
            for (int i = tid; i < m; i += 256) {
                int gidx = cbase + i;
                int lo = 0, hi = ncc - 1;
                while (lo < hi) {
                    int mid = (lo + hi + 1) >> 1;
                    if (ps[mid] <= gidx) lo = mid; else hi = mid - 1;
                }
                int off = gidx - ps[lo];
                pairs[i] = sw[(size_t)lo * epc + rs[lo] + off];
            }
            __syncthreads();
            for (int k = 0; k < m; ++k) {
                int2 p = pairs[k];
                if ((p.x >> 17) == node) {
                    GLOAD(p, f0, f1, f2, f3)
                    GACC(p, f0, f1, f2, f3)
                }
            }
            __syncthreads();
        }
    }
    #undef GLOAD
    #undef GACC

    int node0 = b * RANGE + node;
    if (node0 < n) {
        float* o = out + (size_t)node0 * N_OUT + cg8;
        *reinterpret_cast<float4*>(o + 0) = acc01;
        *reinterpret_cast<float4*>(o + 4) = acc23;
    }
}

// ---------------- Fallback: fused (no workspace) ----------------
__global__ __launch_bounds__(256) void fused_edge(
    const float* __restrict__ feat, const float* __restrict__ W,
    const float* __restrict__ edge_w, const int* __restrict__ src,
    const int* __restrict__ dst, float* __restrict__ out, int E)
{
    __shared__ float Ws[N_IN * N_OUT];
    for (int i = threadIdx.x; i < (N_IN * N_OUT) / 4; i += 256)
        reinterpret_cast<float4*>(Ws)[i] = reinterpret_cast<const float4*>(W)[i];
    __syncthreads();
    int gid = blockIdx.x * 256 + threadIdx.x;
    int e = gid >> 3;
    if (e >= E) return;
    int cg = (gid & 7) * 4;
    int s = src[e];
    int d = dst[e];
    float w = edge_w[e];
    const float4* frow = reinterpret_cast<const float4*>(feat + (size_t)s * N_IN);
    float4 acc = make_float4(0.f, 0.f, 0.f, 0.f);
    #pragma unroll
    for (int k4 = 0; k4 < N_IN / 4; ++k4) {
        float4 f = frow[k4];
        int k = k4 * 4;
        float4 w0 = *reinterpret_cast<const float4*>(&Ws[(k + 0) * N_OUT + cg]);
        float4 w1 = *reinterpret_cast<const float4*>(&Ws[(k + 1) * N_OUT + cg]);
        float4 w2 = *reinterpret_cast<const float4*>(&Ws[(k + 2) * N_OUT + cg]);
        float4 w3 = *reinterpret_cast<const float4*>(&Ws[(k + 3) * N_OUT + cg]);
        acc.x += f.x * w0.x + f.y * w1.x + f.z * w2.x + f.w * w3.x;
        acc.y += f.x * w0.y + f.y * w1.y + f.z * w2.y + f.w * w3.y;
        acc.z += f.x * w0.z + f.y * w1.z + f.z * w2.z + f.w * w3.z;
        acc.w += f.x * w0.w + f.y * w1.w + f.z * w2.w + f.w * w3.w;
    }
    float* o = out + (size_t)d * N_OUT + cg;
    atomicAdd(o + 0, acc.x * w);
    atomicAdd(o + 1, acc.y * w);
    atomicAdd(o + 2, acc.z * w);
    atomicAdd(o + 3, acc.w * w);
}

extern "C" void kernel_launch(void* const* d_in, const int* in_sizes, int n_in,
                              void* d_out, int out_size, void* d_ws, size_t ws_size,
                              hipStream_t stream) {
    const float* feat   = (const float*)d_in[0];
    const float* W      = (const float*)d_in[1];
    const float* edge_w = (const float*)d_in[2];
    const int*   src    = (const int*)d_in[3];
    const int*   dst    = (const int*)d_in[4];
    float* out = (float*)d_out;

    int n = in_sizes[0] / N_IN;   // 100000
    int E = in_sizes[2];          // 1600000

    int NB  = (n + RANGE - 1) / RANGE;             // 1563
    int ncc = NCC;                                 // 256
    int epc = (((E + ncc - 1) / ncc) + 3) & ~3;    // 6252 (x4 for 16B alignment)

    size_t off_h   = 0;
    size_t off_tbl = (off_h + (size_t)n * N_OUT * sizeof(__half) + 15) & ~(size_t)15;
    size_t off_sw  = (off_tbl + (size_t)ncc * (NB + 1) * sizeof(int) + 15) & ~(size_t)15;
    size_t need    = off_sw + (size_t)ncc * epc * sizeof(int2);

    bool ok = (ws_size >= need) && (n <= (1 << 17)) && (NB <= MAXNB) &&
              (epc <= CAP);

    if (ok) {
        char* ws = (char*)d_ws;
        __half* h  = (__half*)(ws + off_h);
        int*   tbl = (int*)(ws + off_tbl);
        int2*  sw  = (int2*)(ws + off_sw);

        int gemm_blocks = (int)(((long)n * 8 + FBLK - 1) / FBLK);   // 1563
        gemm_part_k<<<ncc + gemm_blocks, FBLK, 0, stream>>>(
            feat, W, src, dst, edge_w, h, tbl, sw, n, E, NB, epc, ncc);
        conv6_k<<<NB, 256, 0, stream>>>(h, sw, tbl, out, n, NB, ncc, epc);
    } else {
        hipError_t _e = hipMemsetAsync(d_out, 0, (size_t)out_size * sizeof(float), stream);
        (void)_e;
        long sthreads = (long)E * 8;
        fused_edge<<<(int)((sthreads + 255) / 256), 256, 0, stream>>>(feat, W, edge_w, src, dst, out, E);
    }
}

// Round 18
// 75.489 us; speedup vs baseline: 1.0467x; 1.0467x over previous
//
#include <hip/hip_runtime.h>
#include <hip/hip_fp16.h>

constexpr int N_IN    = 128;
constexpr int N_OUT   = 32;
constexpr int LOG_R   = 6;
constexpr int RANGE   = 1 << LOG_R;  // 64 nodes per bucket
constexpr int MAXNB   = 2048;        // max buckets (LDS hist)
constexpr int NCC     = 256;         // edge chunks
constexpr int FBLK    = 1024;        // fused kernel threads (short chains)
constexpr int CHUNK_P = 2048;        // staged pairs per conv block (fast path)

union H4 { uint2 u; __half2 h2[2]; };
union H8 { uint4 u; __half2 h2[4]; };

// ---------------- fused: partition role (blocks 0..ncc-1) + gemm role ------
// Roles are data-independent; co-scheduling fills latency bubbles.
// LDS overlay: partition uses hist[2048](8KB)+wscan[1024](4KB); gemm uses
// Ws[128*32](16KB). One 16KB raw buffer serves both.
__global__ __launch_bounds__(FBLK) void gemm_part_k(
    const float* __restrict__ feat, const float* __restrict__ W,
    const int* __restrict__ src, const int* __restrict__ dst,
    const float* __restrict__ ew, __half* __restrict__ h,
    int* __restrict__ tbl, int2* __restrict__ sw,
    int n, int E, int NB, int epc, int ncc)
{
    __shared__ __align__(16) char smem[N_IN * N_OUT * sizeof(float)];  // 16 KB
    const int tid = threadIdx.x;

    if ((int)blockIdx.x < ncc) {
        // ================= partition role =================
        int* hist  = (int*)smem;                    // 8 KB
        int* wscan = (int*)(smem + MAXNB * 4);      // 4 KB

        const int c   = blockIdx.x;
        const int e0  = c * epc;
        const int e1  = min(e0 + epc, E);
        const int m   = max(e1 - e0, 0);
        const int m4  = m & ~3;
        const int slots = (NB + FBLK - 1) / FBLK;

        for (int i = tid; i < NB; i += FBLK) hist[i] = 0;
        __syncthreads();

        // pass 1: histogram (int4 loads, 4 independent atomics per iter)
        for (int o = tid * 4; o < m4; o += FBLK * 4) {
            int4 dv = *reinterpret_cast<const int4*>(dst + e0 + o);
            atomicAdd(&hist[dv.x >> LOG_R], 1);
            atomicAdd(&hist[dv.y >> LOG_R], 1);
            atomicAdd(&hist[dv.z >> LOG_R], 1);
            atomicAdd(&hist[dv.w >> LOG_R], 1);
        }
        if (m4 + tid < m) atomicAdd(&hist[dst[e0 + m4 + tid] >> LOG_R], 1);
        __syncthreads();

        // exclusive scan over NB counters
        int tsum = 0;
        int base = tid * slots;
        for (int j = 0; j < slots; ++j) {
            int idx = base + j;
            if (idx < NB) tsum += hist[idx];
        }
        wscan[tid] = tsum;
        __syncthreads();
        for (int off = 1; off < FBLK; off <<= 1) {
            int x = (tid >= off) ? wscan[tid - off] : 0;
            __syncthreads();
            wscan[tid] += x;
            __syncthreads();
        }
        int run = wscan[tid] - tsum;
        __syncthreads();
        for (int j = 0; j < slots; ++j) {
            int idx = base + j;
            if (idx < NB) {
                int cval = hist[idx];
                tbl[(size_t)c * (NB + 1) + idx] = run;
                hist[idx] = run;                        // becomes cursor
                run += cval;
            }
        }
        if (tid == 0) tbl[(size_t)c * (NB + 1) + NB] = m;
        __syncthreads();

        // pass 2: scatter pairs (vectorized reads; src lines L2-hot from pass 1)
        int2* outp = sw + (size_t)c * epc;
        for (int o = tid * 4; o < m4; o += FBLK * 4) {
            int4   sv = *reinterpret_cast<const int4*>(src + e0 + o);
            int4   dv = *reinterpret_cast<const int4*>(dst + e0 + o);
            float4 wv = *reinterpret_cast<const float4*>(ew + e0 + o);
            int p0 = atomicAdd(&hist[dv.x >> LOG_R], 1);
            int p1 = atomicAdd(&hist[dv.y >> LOG_R], 1);
            int p2 = atomicAdd(&hist[dv.z >> LOG_R], 1);
            int p3 = atomicAdd(&hist[dv.w >> LOG_R], 1);
            outp[p0] = make_int2(sv.x | ((dv.x & (RANGE - 1)) << 17), __float_as_int(wv.x));
            outp[p1] = make_int2(sv.y | ((dv.y & (RANGE - 1)) << 17), __float_as_int(wv.y));
            outp[p2] = make_int2(sv.z | ((dv.z & (RANGE - 1)) << 17), __float_as_int(wv.z));
            outp[p3] = make_int2(sv.w | ((dv.w & (RANGE - 1)) << 17), __float_as_int(wv.w));
        }
        if (m4 + tid < m) {
            int e = e0 + m4 + tid;
            int d = dst[e];
            int pos = atomicAdd(&hist[d >> LOG_R], 1);
            outp[pos] = make_int2(src[e] | ((d & (RANGE - 1)) << 17), __float_as_int(ew[e]));
        }
    } else {
        // ================= gemm role =================
        float* Ws = (float*)smem;                   // 16 KB
        for (int i = tid; i < (N_IN * N_OUT) / 4; i += FBLK)
            reinterpret_cast<float4*>(Ws)[i] = reinterpret_cast<const float4*>(W)[i];
        __syncthreads();

        int gid = ((int)blockIdx.x - ncc) * FBLK + tid;
        int row = gid >> 3;
        if (row >= n) return;
        int cg = (gid & 7) * 4;

        const float4* frow = reinterpret_cast<const float4*>(feat + (size_t)row * N_IN);
        float4 acc = make_float4(0.f, 0.f, 0.f, 0.f);
        #pragma unroll
        for (int k4 = 0; k4 < N_IN / 4; ++k4) {
            float4 f = frow[k4];
            int k = k4 * 4;
            float4 w0 = *reinterpret_cast<const float4*>(&Ws[(k + 0) * N_OUT + cg]);
            float4 w1 = *reinterpret_cast<const float4*>(&Ws[(k + 1) * N_OUT + cg]);
            float4 w2 = *reinterpret_cast<const float4*>(&Ws[(k + 2) * N_OUT + cg]);
            float4 w3 = *reinterpret_cast<const float4*>(&Ws[(k + 3) * N_OUT + cg]);
            acc.x += f.x * w0.x + f.y * w1.x + f.z * w2.x + f.w * w3.x;
            acc.y += f.x * w0.y + f.y * w1.y + f.z * w2.y + f.w * w3.y;
            acc.z += f.x * w0.z + f.y * w1.z + f.z * w2.z + f.w * w3.z;
            acc.w += f.x * w0.w + f.y * w1.w + f.z * w2.w + f.w * w3.w;
        }
        H4 v;
        v.h2[0] = __float22half2_rn(make_float2(acc.x, acc.y));
        v.h2[1] = __float22half2_rn(make_float2(acc.z, acc.w));
        *reinterpret_cast<uint2*>(h + (size_t)row * N_OUT + cg) = v.u;
    }
}

// ---------------- conv6: single-read stage + u16 order + 8-wide gather -----
__global__ __launch_bounds__(256) void conv6_k(
    const __half* __restrict__ h, const int2* __restrict__ sw,
    const int* __restrict__ tbl, float* __restrict__ out,
    int n, int NB, int ncc, int epc)
{
    __shared__ int2 pairs[CHUNK_P];            // 16 KB
    __shared__ unsigned short order[CHUNK_P];  // 4 KB
    __shared__ int cnt[RANGE];
    __shared__ int sc[RANGE];
    __shared__ int start[RANGE + 1];
    __shared__ int cur[RANGE];
    __shared__ int rs[NCC];
    __shared__ int ps[NCC + 1];
    __shared__ int stmp[256];

    const int b    = blockIdx.x;
    const int tid  = threadIdx.x;
    const int node = tid >> 2;          // 0..63 (group of 4)
    const int cg8  = (tid & 3) * 8;     // 8 f16 columns per thread

    int len = 0;
    if (tid < ncc) {
        int s0 = tbl[(size_t)tid * (NB + 1) + b];
        int s1 = tbl[(size_t)tid * (NB + 1) + b + 1];
        rs[tid] = s0;
        len = s1 - s0;
    }
    stmp[tid] = len;
    __syncthreads();
    for (int off = 1; off < 256; off <<= 1) {
        int x = (tid >= off) ? stmp[tid - off] : 0;
        __syncthreads();
        stmp[tid] += x;
        __syncthreads();
    }
    ps[tid + 1] = stmp[tid];
    if (tid == 0) ps[0] = 0;
    __syncthreads();
    const int deg = ps[ncc];

    float4 acc01 = make_float4(0.f, 0.f, 0.f, 0.f);
    float4 acc23 = make_float4(0.f, 0.f, 0.f, 0.f);

    #define GLOAD(p, f0, f1, f2, f3)                                           \
        H8 _x##f0;                                                             \
        _x##f0.u = *reinterpret_cast<const uint4*>(                            \
            h + (size_t)((p).x & 0x1FFFF) * N_OUT + cg8);                      \
        float2 f0 = __half22float2(_x##f0.h2[0]);                              \
        float2 f1 = __half22float2(_x##f0.h2[1]);                              \
        float2 f2 = __half22float2(_x##f0.h2[2]);                              \
        float2 f3 = __half22float2(_x##f0.h2[3]);
    #define GACC(p, f0, f1, f2, f3)                                            \
    {                                                                          \
        float wv = __int_as_float((p).y);                                      \
        acc01.x += f0.x * wv; acc01.y += f0.y * wv;                            \
        acc01.z += f1.x * wv; acc01.w += f1.y * wv;                            \
        acc23.x += f2.x * wv; acc23.y += f2.y * wv;                            \
        acc23.z += f3.x * wv; acc23.w += f3.y * wv;                            \
    }

    if (deg <= CHUNK_P) {
        if (tid < RANGE) cnt[tid] = 0;
        __syncthreads();

        {
            int d0 = ps[tid];
            int l  = ps[tid + 1] - d0;
            const int2* sp = sw + (size_t)tid * epc + rs[tid];
            for (int j = 0; j < l; ++j) {
                int2 p = sp[j];
                pairs[d0 + j] = p;
                atomicAdd(&cnt[p.x >> 17], 1);
            }
        }
        __syncthreads();

        int v = 0;
        if (tid < RANGE) { v = cnt[tid]; sc[tid] = v; }
        __syncthreads();
        #pragma unroll
        for (int off = 1; off < RANGE; off <<= 1) {
            int x = (tid < RANGE && tid >= off) ? sc[tid - off] : 0;
            __syncthreads();
            if (tid < RANGE) sc[tid] += x;
            __syncthreads();
        }
        if (tid < RANGE) { start[tid] = sc[tid] - v; cur[tid] = sc[tid] - v; }
        if (tid == RANGE - 1) start[RANGE] = sc[RANGE - 1];
        __syncthreads();

        for (int i = tid; i < deg; i += 256) {
            int loc = pairs[i].x >> 17;
            int pos = atomicAdd(&cur[loc], 1);
            order[pos] = (unsigned short)i;
        }
        __syncthreads();

        int k  = start[node];
        int ke = start[node + 1];
        // 8-wide batch for deep MLP
        for (; k + 7 < ke; k += 8) {
            int2 q0 = pairs[order[k + 0]], q1 = pairs[order[k + 1]];
            int2 q2 = pairs[order[k + 2]], q3 = pairs[order[k + 3]];
            int2 q4 = pairs[order[k + 4]], q5 = pairs[order[k + 5]];
            int2 q6 = pairs[order[k + 6]], q7 = pairs[order[k + 7]];
            GLOAD(q0, m0, m1, m2, m3)
            GLOAD(q1, n0, n1, n2, n3)
            GLOAD(q2, o0, o1, o2, o3)
            GLOAD(q3, p0, p1, p2, p3)
            GLOAD(q4, r0, r1, r2, r3)
            GLOAD(q5, s0, s1, s2, s3)
            GLOAD(q6, t0, t1, t2, t3)
            GLOAD(q7, u0, u1, u2, u3)
            GACC(q0, m0, m1, m2, m3)
            GACC(q1, n0, n1, n2, n3)
            GACC(q2, o0, o1, o2, o3)
            GACC(q3, p0, p1, p2, p3)
            GACC(q4, r0, r1, r2, r3)
            GACC(q5, s0, s1, s2, s3)
            GACC(q6, t0, t1, t2, t3)
            GACC(q7, u0, u1, u2, u3)
        }
        for (; k + 3 < ke; k += 4) {
            int2 q0 = pairs[order[k + 0]], q1 = pairs[order[k + 1]];
            int2 q2 = pairs[order[k + 2]], q3 = pairs[order[k + 3]];
            GLOAD(q0, a0, a1, a2, a3)
            GLOAD(q1, b0, b1, b2, b3)
            GLOAD(q2, c0, c1, c2, c3)
            GLOAD(q3, d0, d1, d2, d3)
            GACC(q0, a0, a1, a2, a3)
            GACC(q1, b0, b1, b2, b3)
            GACC(q2, c0, c1, c2, c3)
            GACC(q3, d0, d1, d2, d3)
        }
        for (; k < ke; ++k) {
            int2 q = pairs[order[k]];
            GLOAD(q, e0, e1, e2, e3)
            GACC(q, e0, e1, e2, e3)
        }
    } else {
        for (int cbase = 0; cbase < deg; cbase += CHUNK_P) {
            const int m = min(CHUNK_P, deg - cbase);
            for (int i = tid; i < m; i += 256) {
                int gidx = cbase + i;
                int lo = 0, hi = ncc - 1;
                while (lo < hi) {
                    int mid = (lo + hi + 1) >> 1;
                    if (ps[mid] <= gidx) lo = mid; else hi = mid - 1;
                }
                int off = gidx - ps[lo];
                pairs[i] = sw[(size_t)lo * epc + rs[lo] + off];
            }
            __syncthreads();
            for (int k = 0; k < m; ++k) {
                int2 p = pairs[k];
                if ((p.x >> 17) == node) {
                    GLOAD(p, f0, f1, f2, f3)
                    GACC(p, f0, f1, f2, f3)
                }
            }
            __syncthreads();
        }
    }
    #undef GLOAD
    #undef GACC

    int node0 = b * RANGE + node;
    if (node0 < n) {
        float* o = out + (size_t)node0 * N_OUT + cg8;
        *reinterpret_cast<float4*>(o + 0) = acc01;
        *reinterpret_cast<float4*>(o + 4) = acc23;
    }
}

// ---------------- Fallback: fused (no workspace) ----------------
__global__ __launch_bounds__(256) void fused_edge(
    const float* __restrict__ feat, const float* __restrict__ W,
    const float* __restrict__ edge_w, const int* __restrict__ src,
    const int* __restrict__ dst, float* __restrict__ out, int E)
{
    __shared__ float Ws[N_IN * N_OUT];
    for (int i = threadIdx.x; i < (N_IN * N_OUT) / 4; i += 256)
        reinterpret_cast<float4*>(Ws)[i] = reinterpret_cast<const float4*>(W)[i];
    __syncthreads();
    int gid = blockIdx.x * 256 + threadIdx.x;
    int e = gid >> 3;
    if (e >= E) return;
    int cg = (gid & 7) * 4;
    int s = src[e];
    int d = dst[e];
    float w = edge_w[e];
    const float4* frow = reinterpret_cast<const float4*>(feat + (size_t)s * N_IN);
    float4 acc = make_float4(0.f, 0.f, 0.f, 0.f);
    #pragma unroll
    for (int k4 = 0; k4 < N_IN / 4; ++k4) {
        float4 f = frow[k4];
        int k = k4 * 4;
        float4 w0 = *reinterpret_cast<const float4*>(&Ws[(k + 0) * N_OUT + cg]);
        float4 w1 = *reinterpret_cast<const float4*>(&Ws[(k + 1) * N_OUT + cg]);
        float4 w2 = *reinterpret_cast<const float4*>(&Ws[(k + 2) * N_OUT + cg]);
        float4 w3 = *reinterpret_cast<const float4*>(&Ws[(k + 3) * N_OUT + cg]);
        acc.x += f.x * w0.x + f.y * w1.x + f.z * w2.x + f.w * w3.x;
        acc.y += f.x * w0.y + f.y * w1.y + f.z * w2.y + f.w * w3.y;
        acc.z += f.x * w0.z + f.y * w1.z + f.z * w2.z + f.w * w3.z;
        acc.w += f.x * w0.w + f.y * w1.w + f.z * w2.w + f.w * w3.w;
    }
    float* o = out + (size_t)d * N_OUT + cg;
    atomicAdd(o + 0, acc.x * w);
    atomicAdd(o + 1, acc.y * w);
    atomicAdd(o + 2, acc.z * w);
    atomicAdd(o + 3, acc.w * w);
}

extern "C" void kernel_launch(void* const* d_in, const int* in_sizes, int n_in,
                              void* d_out, int out_size, void* d_ws, size_t ws_size,
                              hipStream_t stream) {
    const float* feat   = (const float*)d_in[0];
    const float* W      = (const float*)d_in[1];
    const float* edge_w = (const float*)d_in[2];
    const int*   src    = (const int*)d_in[3];
    const int*   dst    = (const int*)d_in[4];
    float* out = (float*)d_out;

    int n = in_sizes[0] / N_IN;   // 100000
    int E = in_sizes[2];          // 1600000

    int NB  = (n + RANGE - 1) / RANGE;             // 1563
    int ncc = NCC;                                 // 256
    int epc = (((E + ncc - 1) / ncc) + 3) & ~3;    // 6252 (x4 for 16B alignment)

    size_t off_h   = 0;
    size_t off_tbl = (off_h + (size_t)n * N_OUT * sizeof(__half) + 15) & ~(size_t)15;
    size_t off_sw  = (off_tbl + (size_t)ncc * (NB + 1) * sizeof(int) + 15) & ~(size_t)15;
    size_t need    = off_sw + (size_t)ncc * epc * sizeof(int2);

    bool ok = (ws_size >= need) && (n <= (1 << 17)) && (NB <= MAXNB);

    if (ok) {
        char* ws = (char*)d_ws;
        __half* h  = (__half*)(ws + off_h);
        int*   tbl = (int*)(ws + off_tbl);
        int2*  sw  = (int2*)(ws + off_sw);

        int gemm_blocks = (int)(((long)n * 8 + FBLK - 1) / FBLK);   // 782
        gemm_part_k<<<ncc + gemm_blocks, FBLK, 0, stream>>>(
            feat, W, src, dst, edge_w, h, tbl, sw, n, E, NB, epc, ncc);
        conv6_k<<<NB, 256, 0, stream>>>(h, sw, tbl, out, n, NB, ncc, epc);
    } else {
        hipError_t _e = hipMemsetAsync(d_out, 0, (size_t)out_size * sizeof(float), stream);
        (void)_e;
        long sthreads = (long)E * 8;
        fused_edge<<<(int)((sthreads + 255) / 256), 256, 0, stream>>>(feat, W, edge_w, src, dst, out, E);
    }
}

// Round 19
// 71.572 us; speedup vs baseline: 1.1040x; 1.0547x over previous
//
#include <hip/hip_runtime.h>
#include <hip/hip_fp16.h>

constexpr int N_IN    = 128;
constexpr int N_OUT   = 32;
constexpr int LOG_R   = 6;
constexpr int RANGE   = 1 << LOG_R;  // 64 nodes per bucket
constexpr int MAXNB   = 2048;        // max buckets (LDS hist)
constexpr int NCC     = 256;         // edge chunks
constexpr int FBLK    = 512;         // fused kernel threads (R15 best config)
constexpr int CHUNK_P = 2048;        // staged pairs per conv block (fast path)

union H4 { uint2 u; __half2 h2[2]; };
union H8 { uint4 u; __half2 h2[4]; };

// ---------------- fused: partition role (blocks 0..ncc-1) + gemm role ------
// Best-measured config (R15, 71.9 us total). Roles are data-independent;
// co-scheduling fills latency bubbles. LDS overlay: partition uses
// hist[2048](8KB)+wscan[512](2KB); gemm uses Ws[128*32](16KB).
__global__ __launch_bounds__(FBLK) void gemm_part_k(
    const float* __restrict__ feat, const float* __restrict__ W,
    const int* __restrict__ src, const int* __restrict__ dst,
    const float* __restrict__ ew, __half* __restrict__ h,
    int* __restrict__ tbl, int2* __restrict__ sw,
    int n, int E, int NB, int epc, int ncc)
{
    __shared__ __align__(16) char smem[N_IN * N_OUT * sizeof(float)];  // 16 KB
    const int tid = threadIdx.x;

    if ((int)blockIdx.x < ncc) {
        // ================= partition role =================
        int* hist  = (int*)smem;                    // 8 KB
        int* wscan = (int*)(smem + MAXNB * 4);      // 2 KB

        const int c   = blockIdx.x;
        const int e0  = c * epc;
        const int e1  = min(e0 + epc, E);
        const int m   = max(e1 - e0, 0);
        const int m4  = m & ~3;
        const int slots = (NB + FBLK - 1) / FBLK;

        for (int i = tid; i < NB; i += FBLK) hist[i] = 0;
        __syncthreads();

        // pass 1: histogram (int4 loads, 4 independent atomics per iter)
        for (int o = tid * 4; o < m4; o += FBLK * 4) {
            int4 dv = *reinterpret_cast<const int4*>(dst + e0 + o);
            atomicAdd(&hist[dv.x >> LOG_R], 1);
            atomicAdd(&hist[dv.y >> LOG_R], 1);
            atomicAdd(&hist[dv.z >> LOG_R], 1);
            atomicAdd(&hist[dv.w >> LOG_R], 1);
        }
        if (m4 + tid < m) atomicAdd(&hist[dst[e0 + m4 + tid] >> LOG_R], 1);
        __syncthreads();

        // exclusive scan over NB counters
        int tsum = 0;
        int base = tid * slots;
        for (int j = 0; j < slots; ++j) {
            int idx = base + j;
            if (idx < NB) tsum += hist[idx];
        }
        wscan[tid] = tsum;
        __syncthreads();
        for (int off = 1; off < FBLK; off <<= 1) {
            int x = (tid >= off) ? wscan[tid - off] : 0;
            __syncthreads();
            wscan[tid] += x;
            __syncthreads();
        }
        int run = wscan[tid] - tsum;
        __syncthreads();
        for (int j = 0; j < slots; ++j) {
            int idx = base + j;
            if (idx < NB) {
                int cval = hist[idx];
                tbl[(size_t)c * (NB + 1) + idx] = run;
                hist[idx] = run;                        // becomes cursor
                run += cval;
            }
        }
        if (tid == 0) tbl[(size_t)c * (NB + 1) + NB] = m;
        __syncthreads();

        // pass 2: scatter pairs (vectorized reads; lines L2-hot from pass 1)
        int2* outp = sw + (size_t)c * epc;
        for (int o = tid * 4; o < m4; o += FBLK * 4) {
            int4   sv = *reinterpret_cast<const int4*>(src + e0 + o);
            int4   dv = *reinterpret_cast<const int4*>(dst + e0 + o);
            float4 wv = *reinterpret_cast<const float4*>(ew + e0 + o);
            int p0 = atomicAdd(&hist[dv.x >> LOG_R], 1);
            int p1 = atomicAdd(&hist[dv.y >> LOG_R], 1);
            int p2 = atomicAdd(&hist[dv.z >> LOG_R], 1);
            int p3 = atomicAdd(&hist[dv.w >> LOG_R], 1);
            outp[p0] = make_int2(sv.x | ((dv.x & (RANGE - 1)) << 17), __float_as_int(wv.x));
            outp[p1] = make_int2(sv.y | ((dv.y & (RANGE - 1)) << 17), __float_as_int(wv.y));
            outp[p2] = make_int2(sv.z | ((dv.z & (RANGE - 1)) << 17), __float_as_int(wv.z));
            outp[p3] = make_int2(sv.w | ((dv.w & (RANGE - 1)) << 17), __float_as_int(wv.w));
        }
        if (m4 + tid < m) {
            int e = e0 + m4 + tid;
            int d = dst[e];
            int pos = atomicAdd(&hist[d >> LOG_R], 1);
            outp[pos] = make_int2(src[e] | ((d & (RANGE - 1)) << 17), __float_as_int(ew[e]));
        }
    } else {
        // ================= gemm role =================
        float* Ws = (float*)smem;                   // 16 KB
        for (int i = tid; i < (N_IN * N_OUT) / 4; i += FBLK)
            reinterpret_cast<float4*>(Ws)[i] = reinterpret_cast<const float4*>(W)[i];
        __syncthreads();

        int gid = ((int)blockIdx.x - ncc) * FBLK + tid;
        int row = gid >> 3;
        if (row >= n) return;
        int cg = (gid & 7) * 4;

        const float4* frow = reinterpret_cast<const float4*>(feat + (size_t)row * N_IN);
        float4 acc = make_float4(0.f, 0.f, 0.f, 0.f);
        #pragma unroll
        for (int k4 = 0; k4 < N_IN / 4; ++k4) {
            float4 f = frow[k4];
            int k = k4 * 4;
            float4 w0 = *reinterpret_cast<const float4*>(&Ws[(k + 0) * N_OUT + cg]);
            float4 w1 = *reinterpret_cast<const float4*>(&Ws[(k + 1) * N_OUT + cg]);
            float4 w2 = *reinterpret_cast<const float4*>(&Ws[(k + 2) * N_OUT + cg]);
            float4 w3 = *reinterpret_cast<const float4*>(&Ws[(k + 3) * N_OUT + cg]);
            acc.x += f.x * w0.x + f.y * w1.x + f.z * w2.x + f.w * w3.x;
            acc.y += f.x * w0.y + f.y * w1.y + f.z * w2.y + f.w * w3.y;
            acc.z += f.x * w0.z + f.y * w1.z + f.z * w2.z + f.w * w3.z;
            acc.w += f.x * w0.w + f.y * w1.w + f.z * w2.w + f.w * w3.w;
        }
        H4 v;
        v.h2[0] = __float22half2_rn(make_float2(acc.x, acc.y));
        v.h2[1] = __float22half2_rn(make_float2(acc.z, acc.w));
        *reinterpret_cast<uint2*>(h + (size_t)row * N_OUT + cg) = v.u;
    }
}

// ---------------- conv6: single-read stage + u16 order + 8-wide gather -----
__global__ __launch_bounds__(256) void conv6_k(
    const __half* __restrict__ h, const int2* __restrict__ sw,
    const int* __restrict__ tbl, float* __restrict__ out,
    int n, int NB, int ncc, int epc)
{
    __shared__ int2 pairs[CHUNK_P];            // 16 KB
    __shared__ unsigned short order[CHUNK_P];  // 4 KB
    __shared__ int cnt[RANGE];
    __shared__ int sc[RANGE];
    __shared__ int start[RANGE + 1];
    __shared__ int cur[RANGE];
    __shared__ int rs[NCC];
    __shared__ int ps[NCC + 1];
    __shared__ int stmp[256];

    const int b    = blockIdx.x;
    const int tid  = threadIdx.x;
    const int node = tid >> 2;          // 0..63 (group of 4)
    const int cg8  = (tid & 3) * 8;     // 8 f16 columns per thread

    int len = 0;
    if (tid < ncc) {
        int s0 = tbl[(size_t)tid * (NB + 1) + b];
        int s1 = tbl[(size_t)tid * (NB + 1) + b + 1];
        rs[tid] = s0;
        len = s1 - s0;
    }
    stmp[tid] = len;
    __syncthreads();
    for (int off = 1; off < 256; off <<= 1) {
        int x = (tid >= off) ? stmp[tid - off] : 0;
        __syncthreads();
        stmp[tid] += x;
        __syncthreads();
    }
    ps[tid + 1] = stmp[tid];
    if (tid == 0) ps[0] = 0;
    __syncthreads();
    const int deg = ps[ncc];

    float4 acc01 = make_float4(0.f, 0.f, 0.f, 0.f);
    float4 acc23 = make_float4(0.f, 0.f, 0.f, 0.f);

    #define GLOAD(p, f0, f1, f2, f3)                                           \
        H8 _x##f0;                                                             \
        _x##f0.u = *reinterpret_cast<const uint4*>(                            \
            h + (size_t)((p).x & 0x1FFFF) * N_OUT + cg8);                      \
        float2 f0 = __half22float2(_x##f0.h2[0]);                              \
        float2 f1 = __half22float2(_x##f0.h2[1]);                              \
        float2 f2 = __half22float2(_x##f0.h2[2]);                              \
        float2 f3 = __half22float2(_x##f0.h2[3]);
    #define GACC(p, f0, f1, f2, f3)                                            \
    {                                                                          \
        float wv = __int_as_float((p).y);                                      \
        acc01.x += f0.x * wv; acc01.y += f0.y * wv;                            \
        acc01.z += f1.x * wv; acc01.w += f1.y * wv;                            \
        acc23.x += f2.x * wv; acc23.y += f2.y * wv;                            \
        acc23.z += f3.x * wv; acc23.w += f3.y * wv;                            \
    }

    if (deg <= CHUNK_P) {
        if (tid < RANGE) cnt[tid] = 0;
        __syncthreads();

        {
            int d0 = ps[tid];
            int l  = ps[tid + 1] - d0;
            const int2* sp = sw + (size_t)tid * epc + rs[tid];
            for (int j = 0; j < l; ++j) {
                int2 p = sp[j];
                pairs[d0 + j] = p;
                atomicAdd(&cnt[p.x >> 17], 1);
            }
        }
        __syncthreads();

        int v = 0;
        if (tid < RANGE) { v = cnt[tid]; sc[tid] = v; }
        __syncthreads();
        #pragma unroll
        for (int off = 1; off < RANGE; off <<= 1) {
            int x = (tid < RANGE && tid >= off) ? sc[tid - off] : 0;
            __syncthreads();
            if (tid < RANGE) sc[tid] += x;
            __syncthreads();
        }
        if (tid < RANGE) { start[tid] = sc[tid] - v; cur[tid] = sc[tid] - v; }
        if (tid == RANGE - 1) start[RANGE] = sc[RANGE - 1];
        __syncthreads();

        for (int i = tid; i < deg; i += 256) {
            int loc = pairs[i].x >> 17;
            int pos = atomicAdd(&cur[loc], 1);
            order[pos] = (unsigned short)i;
        }
        __syncthreads();

        int k  = start[node];
        int ke = start[node + 1];
        // 8-wide batch for deep MLP
        for (; k + 7 < ke; k += 8) {
            int2 q0 = pairs[order[k + 0]], q1 = pairs[order[k + 1]];
            int2 q2 = pairs[order[k + 2]], q3 = pairs[order[k + 3]];
            int2 q4 = pairs[order[k + 4]], q5 = pairs[order[k + 5]];
            int2 q6 = pairs[order[k + 6]], q7 = pairs[order[k + 7]];
            GLOAD(q0, m0, m1, m2, m3)
            GLOAD(q1, n0, n1, n2, n3)
            GLOAD(q2, o0, o1, o2, o3)
            GLOAD(q3, p0, p1, p2, p3)
            GLOAD(q4, r0, r1, r2, r3)
            GLOAD(q5, s0, s1, s2, s3)
            GLOAD(q6, t0, t1, t2, t3)
            GLOAD(q7, u0, u1, u2, u3)
            GACC(q0, m0, m1, m2, m3)
            GACC(q1, n0, n1, n2, n3)
            GACC(q2, o0, o1, o2, o3)
            GACC(q3, p0, p1, p2, p3)
            GACC(q4, r0, r1, r2, r3)
            GACC(q5, s0, s1, s2, s3)
            GACC(q6, t0, t1, t2, t3)
            GACC(q7, u0, u1, u2, u3)
        }
        for (; k + 3 < ke; k += 4) {
            int2 q0 = pairs[order[k + 0]], q1 = pairs[order[k + 1]];
            int2 q2 = pairs[order[k + 2]], q3 = pairs[order[k + 3]];
            GLOAD(q0, a0, a1, a2, a3)
            GLOAD(q1, b0, b1, b2, b3)
            GLOAD(q2, c0, c1, c2, c3)
            GLOAD(q3, d0, d1, d2, d3)
            GACC(q0, a0, a1, a2, a3)
            GACC(q1, b0, b1, b2, b3)
            GACC(q2, c0, c1, c2, c3)
            GACC(q3, d0, d1, d2, d3)
        }
        for (; k < ke; ++k) {
            int2 q = pairs[order[k]];
            GLOAD(q, e0, e1, e2, e3)
            GACC(q, e0, e1, e2, e3)
        }
    } else {
        for (int cbase = 0; cbase < deg; cbase += CHUNK_P) {
            const int m = min(CHUNK_P, deg - cbase);
            for (int i = tid; i < m; i += 256) {
                int gidx = cbase + i;
                int lo = 0, hi = ncc - 1;
                while (lo < hi) {
                    int mid = (lo + hi + 1) >> 1;
                    if (ps[mid] <= gidx) lo = mid; else hi = mid - 1;
                }
                int off = gidx - ps[lo];
                pairs[i] = sw[(size_t)lo * epc + rs[lo] + off];
            }
            __syncthreads();
            for (int k = 0; k < m; ++k) {
                int2 p = pairs[k];
                if ((p.x >> 17) == node) {
                    GLOAD(p, f0, f1, f2, f3)
                    GACC(p, f0, f1, f2, f3)
                }
            }
            __syncthreads();
        }
    }
    #undef GLOAD
    #undef GACC

    int node0 = b * RANGE + node;
    if (node0 < n) {
        float* o = out + (size_t)node0 * N_OUT + cg8;
        *reinterpret_cast<float4*>(o + 0) = acc01;
        *reinterpret_cast<float4*>(o + 4) = acc23;
    }
}

// ---------------- Fallback: fused (no workspace) ----------------
__global__ __launch_bounds__(256) void fused_edge(
    const float* __restrict__ feat, const float* __restrict__ W,
    const float* __restrict__ edge_w, const int* __restrict__ src,
    const int* __restrict__ dst, float* __restrict__ out, int E)
{
    __shared__ float Ws[N_IN * N_OUT];
    for (int i = threadIdx.x; i < (N_IN * N_OUT) / 4; i += 256)
        reinterpret_cast<float4*>(Ws)[i] = reinterpret_cast<const float4*>(W)[i];
    __syncthreads();
    int gid = blockIdx.x * 256 + threadIdx.x;
    int e = gid >> 3;
    if (e >= E) return;
    int cg = (gid & 7) * 4;
    int s = src[e];
    int d = dst[e];
    float w = edge_w[e];
    const float4* frow = reinterpret_cast<const float4*>(feat + (size_t)s * N_IN);
    float4 acc = make_float4(0.f, 0.f, 0.f, 0.f);
    #pragma unroll
    for (int k4 = 0; k4 < N_IN / 4; ++k4) {
        float4 f = frow[k4];
        int k = k4 * 4;
        float4 w0 = *reinterpret_cast<const float4*>(&Ws[(k + 0) * N_OUT + cg]);
        float4 w1 = *reinterpret_cast<const float4*>(&Ws[(k + 1) * N_OUT + cg]);
        float4 w2 = *reinterpret_cast<const float4*>(&Ws[(k + 2) * N_OUT + cg]);
        float4 w3 = *reinterpret_cast<const float4*>(&Ws[(k + 3) * N_OUT + cg]);
        acc.x += f.x * w0.x + f.y * w1.x + f.z * w2.x + f.w * w3.x;
        acc.y += f.x * w0.y + f.y * w1.y + f.z * w2.y + f.w * w3.y;
        acc.z += f.x * w0.z + f.y * w1.z + f.z * w2.z + f.w * w3.z;
        acc.w += f.x * w0.w + f.y * w1.w + f.z * w2.w + f.w * w3.w;
    }
    float* o = out + (size_t)d * N_OUT + cg;
    atomicAdd(o + 0, acc.x * w);
    atomicAdd(o + 1, acc.y * w);
    atomicAdd(o + 2, acc.z * w);
    atomicAdd(o + 3, acc.w * w);
}

extern "C" void kernel_launch(void* const* d_in, const int* in_sizes, int n_in,
                              void* d_out, int out_size, void* d_ws, size_t ws_size,
                              hipStream_t stream) {
    const float* feat   = (const float*)d_in[0];
    const float* W      = (const float*)d_in[1];
    const float* edge_w = (const float*)d_in[2];
    const int*   src    = (const int*)d_in[3];
    const int*   dst    = (const int*)d_in[4];
    float* out = (float*)d_out;

    int n = in_sizes[0] / N_IN;   // 100000
    int E = in_sizes[2];          // 1600000

    int NB  = (n + RANGE - 1) / RANGE;             // 1563
    int ncc = NCC;                                 // 256
    int epc = (((E + ncc - 1) / ncc) + 3) & ~3;    // 6252 (x4 for 16B alignment)

    size_t off_h   = 0;
    size_t off_tbl = (off_h + (size_t)n * N_OUT * sizeof(__half) + 15) & ~(size_t)15;
    size_t off_sw  = (off_tbl + (size_t)ncc * (NB + 1) * sizeof(int) + 15) & ~(size_t)15;
    size_t need    = off_sw + (size_t)ncc * epc * sizeof(int2);

    bool ok = (ws_size >= need) && (n <= (1 << 17)) && (NB <= MAXNB);

    if (ok) {
        char* ws = (char*)d_ws;
        __half* h  = (__half*)(ws + off_h);
        int*   tbl = (int*)(ws + off_tbl);
        int2*  sw  = (int2*)(ws + off_sw);

        int gemm_blocks = (int)(((long)n * 8 + FBLK - 1) / FBLK);   // 1563
        gemm_part_k<<<ncc + gemm_blocks, FBLK, 0, stream>>>(
            feat, W, src, dst, edge_w, h, tbl, sw, n, E, NB, epc, ncc);
        conv6_k<<<NB, 256, 0, stream>>>(h, sw, tbl, out, n, NB, ncc, epc);
    } else {
        hipError_t _e = hipMemsetAsync(d_out, 0, (size_t)out_size * sizeof(float), stream);
        (void)_e;
        long sthreads = (long)E * 8;
        fused_edge<<<(int)((sthreads + 255) / 256), 256, 0, stream>>>(feat, W, edge_w, src, dst, out, E);
    }
}